// Round 6
// baseline (329.032 us; speedup 1.0000x reference)
//
#include <hip/hip_runtime.h>

// VQ nearest-embedding, fused split-fp16 MFMA, double-buffered LDS, K-split.
// argmin_k ||x-e_k||^2 == argmin_k (0.5*||e_k||^2 - x.e_k).
// x = xh+xl, e = eh+el (fp16 RNE); 3 MFMA terms (hh, hl, lh) - validated R5.
// R6: grid (256 m-blocks x 2 k-splits) -> 2 blocks/CU co-resident to fill
// barrier stalls. Cross-block argmin combine via u64 keys staged in each
// block's OWN d_out region (rows d=2s,2s+1), no atomics, no extra workspace.

typedef __attribute__((ext_vector_type(8))) _Float16 half8v;  // 8 fp16 = 4 VGPRs
typedef __attribute__((ext_vector_type(16))) float floatx16;  // 32x32 acc
typedef unsigned int uint;
typedef unsigned short ushort;
typedef unsigned long long ull;

#define DD 256
#define KK 2048
#define SS 1024
#define NN 32768
#define MT 128      // latents per block
#define NTT 256     // codes per kt tile
#define KSPLIT 2    // codebook halves (blockIdx.y)
#define LDA 24      // LDS row stride in fp16 elems (48 B: 16B-aligned, banks spread)
#define MFMA_F16 __builtin_amdgcn_mfma_f32_32x32x16_f16

union HU { _Float16 f; ushort u; };

__device__ __forceinline__ void split16(float v, ushort& h, ushort& l) {
    HU a, b;
    a.f = (_Float16)v;                       // RNE
    b.f = (_Float16)(v - (float)a.f);
    h = a.u; l = b.u;
}

__device__ __forceinline__ uint mono(float s) {   // order-preserving f32 -> u32
    uint b = __float_as_uint(s);
    return b ^ ((b & 0x80000000u) ? 0xFFFFFFFFu : 0x80000000u);
}

__global__ __launch_bounds__(256) void hn_kernel(const float* __restrict__ emb,
                                                 float* __restrict__ hn) {
    int k = blockIdx.x * 256 + threadIdx.x;
    float a = 0.f;
#pragma unroll 32
    for (int d = 0; d < DD; ++d) { float e = emb[d * KK + k]; a += e * e; }
    hn[k] = 0.5f * a;
}

__global__ __launch_bounds__(512, 4) void vq_fused(
        const float* __restrict__ x, const float* __restrict__ emb,
        const float* __restrict__ hn, float* __restrict__ out) {
    __shared__ ushort Ah[2][MT * LDA], Al[2][MT * LDA];     // 6 KB / buf / plane
    __shared__ ushort Bh[2][NTT * LDA], Bl[2][NTT * LDA];   // 12 KB / buf / plane
    __shared__ float sv[4][MT];
    __shared__ int   sc[4][MT];

    const int tid = threadIdx.x;
    const int lane = tid & 63;
    const int wid = tid >> 6;          // 8 waves: 2(m) x 4(n)
    const int colk = lane & 31;
    const int half = lane >> 5;
    const int wm = (wid & 1) * 64;
    const int wn = (wid >> 1) * 64;

    const int base_n = blockIdx.x * MT;
    const int ks = blockIdx.y;            // codebook half
    const int kbase = ks * (KK / KSPLIT); // 0 or 1024
    const int bq = base_n >> 10;          // batch (SS = 1024)
    const int sb = base_n & (SS - 1);     // spatial base

    // staging assignment (512 threads)
    const int lat_a = tid & 127;          // A: one latent, 4 d's
    const int dqa = (tid >> 7) * 4;
    const int cod_b = tid & 255;          // B: one code, 8 d's
    const int dqb = (tid >> 8) * 8;

    const float* xb = x + ((size_t)bq * DD + dqa) * SS + sb + lat_a;

    floatx16 acc[2][2];
#pragma unroll
    for (int i = 0; i < 2; ++i)
#pragma unroll
        for (int j = 0; j < 2; ++j) acc[i][j] = (floatx16)(0.0f);

    float bestv[2][16];
    int bestc[2][16];
#pragma unroll
    for (int t = 0; t < 2; ++t)
#pragma unroll
        for (int r = 0; r < 16; ++r) { bestv[t][r] = 3.4e38f; bestc[t][r] = 0; }

    float fa[4], fb[8];
    // prefetch chunk 0 (kt=0, dt=0)
#pragma unroll
    for (int i = 0; i < 4; ++i) fa[i] = xb[(size_t)i * SS];
    {
        const float* p = emb + (size_t)dqb * KK + kbase + cod_b;
#pragma unroll
        for (int i = 0; i < 8; ++i) fb[i] = p[(size_t)i * KK];
    }
    // convert chunk 0 -> buffer 0
    {
        ushort h[8], l[8];
#pragma unroll
        for (int i = 0; i < 4; ++i) split16(fa[i], h[i], l[i]);
        uint2 w;
        w.x = (uint)h[0] | ((uint)h[1] << 16);
        w.y = (uint)h[2] | ((uint)h[3] << 16);
        *reinterpret_cast<uint2*>(&Ah[0][lat_a * LDA + dqa]) = w;
        w.x = (uint)l[0] | ((uint)l[1] << 16);
        w.y = (uint)l[2] | ((uint)l[3] << 16);
        *reinterpret_cast<uint2*>(&Al[0][lat_a * LDA + dqa]) = w;
#pragma unroll
        for (int i = 0; i < 8; ++i) split16(fb[i], h[i], l[i]);
        uint4 t;
        t.x = (uint)h[0] | ((uint)h[1] << 16);
        t.y = (uint)h[2] | ((uint)h[3] << 16);
        t.z = (uint)h[4] | ((uint)h[5] << 16);
        t.w = (uint)h[6] | ((uint)h[7] << 16);
        *reinterpret_cast<uint4*>(&Bh[0][cod_b * LDA + dqb]) = t;
        t.x = (uint)l[0] | ((uint)l[1] << 16);
        t.y = (uint)l[2] | ((uint)l[3] << 16);
        t.z = (uint)l[4] | ((uint)l[5] << 16);
        t.w = (uint)l[6] | ((uint)l[7] << 16);
        *reinterpret_cast<uint4*>(&Bl[0][cod_b * LDA + dqb]) = t;
    }
    __syncthreads();

    for (int c = 0; c < 64; ++c) {          // 4 kt x 16 dt chunks of K-depth 16
        const int cur = c & 1, nxt = cur ^ 1;
        // ---- prefetch next chunk's globals (in flight during MFMA) ----
        if (c < 63) {
            const int c1 = c + 1;
            const int kt1 = c1 >> 4;
            const int dt1 = (c1 & 15) * 16;
#pragma unroll
            for (int i = 0; i < 4; ++i) fa[i] = xb[(size_t)(dt1 + i) * SS];
            const float* p = emb + (size_t)(dt1 + dqb) * KK + kbase + kt1 * NTT + cod_b;
#pragma unroll
            for (int i = 0; i < 8; ++i) fb[i] = p[(size_t)i * KK];
        }
        // ---- fragments from current buffer + 12 MFMA (3 terms x 2x2) ----
        const int fo = colk * LDA + half * 8;
        half8v ah0 = *reinterpret_cast<const half8v*>(&Ah[cur][fo + wm * LDA]);
        half8v ah1 = *reinterpret_cast<const half8v*>(&Ah[cur][fo + (wm + 32) * LDA]);
        half8v al0 = *reinterpret_cast<const half8v*>(&Al[cur][fo + wm * LDA]);
        half8v al1 = *reinterpret_cast<const half8v*>(&Al[cur][fo + (wm + 32) * LDA]);
        half8v bh0 = *reinterpret_cast<const half8v*>(&Bh[cur][fo + wn * LDA]);
        half8v bh1 = *reinterpret_cast<const half8v*>(&Bh[cur][fo + (wn + 32) * LDA]);
        half8v bl0 = *reinterpret_cast<const half8v*>(&Bl[cur][fo + wn * LDA]);
        half8v bl1 = *reinterpret_cast<const half8v*>(&Bl[cur][fo + (wn + 32) * LDA]);

        acc[0][0] = MFMA_F16(ah0, bh0, acc[0][0], 0, 0, 0);
        acc[0][0] = MFMA_F16(ah0, bl0, acc[0][0], 0, 0, 0);
        acc[0][0] = MFMA_F16(al0, bh0, acc[0][0], 0, 0, 0);

        acc[0][1] = MFMA_F16(ah0, bh1, acc[0][1], 0, 0, 0);
        acc[0][1] = MFMA_F16(ah0, bl1, acc[0][1], 0, 0, 0);
        acc[0][1] = MFMA_F16(al0, bh1, acc[0][1], 0, 0, 0);

        acc[1][0] = MFMA_F16(ah1, bh0, acc[1][0], 0, 0, 0);
        acc[1][0] = MFMA_F16(ah1, bl0, acc[1][0], 0, 0, 0);
        acc[1][0] = MFMA_F16(al1, bh0, acc[1][0], 0, 0, 0);

        acc[1][1] = MFMA_F16(ah1, bh1, acc[1][1], 0, 0, 0);
        acc[1][1] = MFMA_F16(ah1, bl1, acc[1][1], 0, 0, 0);
        acc[1][1] = MFMA_F16(al1, bh1, acc[1][1], 0, 0, 0);

        // ---- convert prefetched -> write NEXT buffer (overlaps MFMA) ----
        if (c < 63) {
            ushort h[8], l[8];
#pragma unroll
            for (int i = 0; i < 4; ++i) split16(fa[i], h[i], l[i]);
            uint2 w;
            w.x = (uint)h[0] | ((uint)h[1] << 16);
            w.y = (uint)h[2] | ((uint)h[3] << 16);
            *reinterpret_cast<uint2*>(&Ah[nxt][lat_a * LDA + dqa]) = w;
            w.x = (uint)l[0] | ((uint)l[1] << 16);
            w.y = (uint)l[2] | ((uint)l[3] << 16);
            *reinterpret_cast<uint2*>(&Al[nxt][lat_a * LDA + dqa]) = w;
#pragma unroll
            for (int i = 0; i < 8; ++i) split16(fb[i], h[i], l[i]);
            uint4 t;
            t.x = (uint)h[0] | ((uint)h[1] << 16);
            t.y = (uint)h[2] | ((uint)h[3] << 16);
            t.z = (uint)h[4] | ((uint)h[5] << 16);
            t.w = (uint)h[6] | ((uint)h[7] << 16);
            *reinterpret_cast<uint4*>(&Bh[nxt][cod_b * LDA + dqb]) = t;
            t.x = (uint)l[0] | ((uint)l[1] << 16);
            t.y = (uint)l[2] | ((uint)l[3] << 16);
            t.z = (uint)l[4] | ((uint)l[5] << 16);
            t.w = (uint)l[6] | ((uint)l[7] << 16);
            *reinterpret_cast<uint4*>(&Bl[nxt][cod_b * LDA + dqb]) = t;
        }
        // ---- per-kt epilogue: scores -> running per-lane argmin, reset acc ----
        if ((c & 15) == 15) {
            const int kt = c >> 4;
            const int cd0 = kbase + kt * NTT + wn + colk;
            const int cd1 = cd0 + 32;
            const float h0 = hn[cd0];
            const float h1 = hn[cd1];
#pragma unroll
            for (int tm = 0; tm < 2; ++tm) {
#pragma unroll
                for (int r = 0; r < 16; ++r) {
                    float s0 = h0 - acc[tm][0][r];
                    float s1 = h1 - acc[tm][1][r];
                    float v = s0; int cd = cd0;
                    if (s1 < s0) { v = s1; cd = cd1; }   // strict <: smaller code wins
                    if (v < bestv[tm][r]) { bestv[tm][r] = v; bestc[tm][r] = cd; }
                    acc[tm][0][r] = 0.f;
                    acc[tm][1][r] = 0.f;
                }
            }
        }
        __syncthreads();   // single barrier per chunk (dbuf)
    }

    // ---- cross-lane argmin: butterfly over the 32 colk lanes ----
#pragma unroll
    for (int tm = 0; tm < 2; ++tm) {
#pragma unroll
        for (int r = 0; r < 16; ++r) {
            float v = bestv[tm][r];
            int cd = bestc[tm][r];
#pragma unroll
            for (int mk = 1; mk < 32; mk <<= 1) {
                float ov = __shfl_xor(v, mk);
                int oc = __shfl_xor(cd, mk);
                if (ov < v || (ov == v && oc < cd)) { v = ov; cd = oc; }
            }
            if (colk == 0) {
                const int row = (r & 3) + 8 * (r >> 2) + 4 * half;  // verified C/D map
                sv[wid >> 1][wm + tm * 32 + row] = v;
                sc[wid >> 1][wm + tm * 32 + row] = cd;
            }
        }
    }
    __syncthreads();
    // ---- combine 4 n-wave groups, pack u64 key, write to OWN out rows ----
    if (tid < MT) {
        float v = sv[0][tid]; int cd = sc[0][tid];
#pragma unroll
        for (int g = 1; g < 4; ++g) {
            float ov = sv[g][tid]; int oc = sc[g][tid];
            if (ov < v || (ov == v && oc < cd)) { v = ov; cd = oc; }
        }
        ull key = (((ull)mono(v)) << 32) | (uint)cd;
        // rows d = 2*ks + (tid>=64): 64 u64 per 512-B row, inside this
        // m-block's own output region (gather kernel reads then overwrites)
        const int row = 2 * ks + (tid >> 6);
        ull* p = reinterpret_cast<ull*>(out + ((size_t)(bq * DD + row) * SS + sb));
        p[tid & 63] = key;
    }
}

__global__ __launch_bounds__(256) void gather_kernel(
        const float* __restrict__ emb, float* __restrict__ out) {
    __shared__ int bc[MT];
    const int tid = threadIdx.x;
    const int base_n = blockIdx.x * MT;
    const int bq = base_n >> 10;
    const int sb = base_n & (SS - 1);
    // read this block's own key rows (d = 0..3), combine the 2 splits
    if (tid < MT) {
        const int r = tid >> 6;     // row within split
        const int cq = tid & 63;
        const ull* p0 = reinterpret_cast<const ull*>(
                out + ((size_t)(bq * DD + r) * SS + sb));
        const ull* p1 = reinterpret_cast<const ull*>(
                out + ((size_t)(bq * DD + 2 + r) * SS + sb));
        ull k0 = p0[cq], k1 = p1[cq];
        ull kb = k0 < k1 ? k0 : k1;       // min score, tie -> smaller code
        bc[tid] = (int)(uint)(kb & 0xFFFFFFFFull);
    }
    __syncthreads();
    // gather: out[(bq*DD+d)*SS + sb + m] = emb[d*KK + bc[m]]
    {
        const int mq = tid & 31;     // float4 group along m
        const int dg = tid >> 5;     // 0..7, 32 d's each
        const int k0 = bc[mq * 4 + 0];
        const int k1 = bc[mq * 4 + 1];
        const int k2 = bc[mq * 4 + 2];
        const int k3 = bc[mq * 4 + 3];
#pragma unroll 4
        for (int dd = 0; dd < 32; ++dd) {
            const int d = dg * 32 + dd;
            const float* er = emb + (size_t)d * KK;
            float4 o = make_float4(er[k0], er[k1], er[k2], er[k3]);
            reinterpret_cast<float4*>(&out[((size_t)bq * DD + d) * SS + sb])[mq] = o;
        }
    }
}

extern "C" void kernel_launch(void* const* d_in, const int* in_sizes, int n_in,
                              void* d_out, int out_size, void* d_ws, size_t ws_size,
                              hipStream_t stream) {
    const float* x = (const float*)d_in[0];     // (32,256,32,32)
    const float* emb = (const float*)d_in[1];   // (256,2048)
    float* out = (float*)d_out;
    float* hn = (float*)d_ws;                   // 2048 f32 = 8 KB (proven safe)

    hipLaunchKernelGGL(hn_kernel, dim3(KK / 256), dim3(256), 0, stream, emb, hn);
    hipLaunchKernelGGL(vq_fused, dim3(NN / MT, KSPLIT), dim3(512), 0, stream,
                       x, emb, hn, out);
    hipLaunchKernelGGL(gather_kernel, dim3(NN / MT), dim3(256), 0, stream,
                       emb, out);
}

// Round 7
// 278.277 us; speedup vs baseline: 1.1824x; 1.1824x over previous
//
#include <hip/hip_runtime.h>

// VQ nearest-embedding, split-fp16 MFMA (3 terms, validated R5/R6).
// R7: emb pre-split ONCE (prep_e) into fp16 hi/lo planes stored in a donated
// region of d_out (rows d=4..19 of each batch, 2 MB); vq stages B via
// global_load_lds width-16 (no VGPR round-trip, no in-loop B conversion).
// Keys in rows 0..3 of each m-block's own output window (R6-proven); gather
// reads own keys then overwrites its whole window (Eh/El dead by then).

typedef __attribute__((ext_vector_type(8))) _Float16 half8v;  // 8 fp16 = 4 VGPRs
typedef __attribute__((ext_vector_type(16))) float floatx16;  // 32x32 acc
typedef unsigned int uint;
typedef unsigned short ushort;
typedef unsigned long long ull;

#define DD 256
#define KK 2048
#define SS 1024
#define NN 32768
#define MT 128      // latents per block
#define NTT 256     // codes per kt tile
#define KSPLIT 2    // codebook halves
#define LDA 24      // A LDS row stride (ushorts): 48 B, start-banks spread
#define MFMA_F16 __builtin_amdgcn_mfma_f32_32x32x16_f16

union HU { _Float16 f; ushort u; };

__device__ __forceinline__ void split16(float v, ushort& h, ushort& l) {
    HU a, b;
    a.f = (_Float16)v;                       // RNE
    b.f = (_Float16)(v - (float)a.f);
    h = a.u; l = b.u;
}

__device__ __forceinline__ uint mono(float s) {   // order-preserving f32 -> u32
    uint b = __float_as_uint(s);
    return b ^ ((b & 0x80000000u) ? 0xFFFFFFFFu : 0x80000000u);
}

// Donated area in d_out: rows d=4..19 of each batch (16 rows x 1024 x 4 B =
// 64 KB contiguous per batch). Linear ushort index j in [0, 2^20) maps to:
__device__ __forceinline__ size_t area_us(uint j) {
    return (size_t)(j >> 15) * 524288u + 8192u + (j & 32767u);
}

__device__ __forceinline__ void glds16(const ushort* g, ushort* l) {
    __builtin_amdgcn_global_load_lds(
        (const __attribute__((address_space(1))) void*)g,
        (__attribute__((address_space(3))) void*)l, 16, 0, 0);
}

__global__ __launch_bounds__(256) void hn_kernel(const float* __restrict__ emb,
                                                 float* __restrict__ hn) {
    int k = blockIdx.x * 256 + threadIdx.x;
    float a = 0.f;
#pragma unroll 32
    for (int d = 0; d < DD; ++d) { float e = emb[d * KK + k]; a += e * e; }
    hn[k] = 0.5f * a;
}

// Split emb into fp16 hi/lo planes, layout j = plane*524288 + k*256 + d
// (K-contiguous per code -> 16-B fragment chunks), placed via area_us.
__global__ __launch_bounds__(256) void prep_e(const float* __restrict__ emb,
                                              ushort* __restrict__ o16) {
    const uint g = blockIdx.x * 256 + threadIdx.x;   // 65536 threads
    const uint k = g & (KK - 1);
    const uint dg = g >> 11;                         // 0..31, 8 d's each
    ushort h[8], l[8];
#pragma unroll
    for (int i = 0; i < 8; ++i) {
        float v = emb[(size_t)(dg * 8 + i) * KK + k];
        split16(v, h[i], l[i]);
    }
    uint4 t;
    const uint j0 = k * 256 + dg * 8;
    t.x = (uint)h[0] | ((uint)h[1] << 16);
    t.y = (uint)h[2] | ((uint)h[3] << 16);
    t.z = (uint)h[4] | ((uint)h[5] << 16);
    t.w = (uint)h[6] | ((uint)h[7] << 16);
    *reinterpret_cast<uint4*>(&o16[area_us(j0)]) = t;
    t.x = (uint)l[0] | ((uint)l[1] << 16);
    t.y = (uint)l[2] | ((uint)l[3] << 16);
    t.z = (uint)l[4] | ((uint)l[5] << 16);
    t.w = (uint)l[6] | ((uint)l[7] << 16);
    *reinterpret_cast<uint4*>(&o16[area_us(j0 + 524288u)]) = t;
}

__global__ __launch_bounds__(512, 2) void vq_fused(
        const float* __restrict__ x, const ushort* __restrict__ e16,
        const float* __restrict__ hn, float* __restrict__ out) {
    __shared__ ushort Ah[2][MT * LDA], Al[2][MT * LDA];   // 6 KB / buf / plane
    __shared__ ushort Bh[2][NTT * 16], Bl[2][NTT * 16];   // 8 KB / buf / plane
    __shared__ float sv[4][MT];
    __shared__ int   sc[4][MT];

    const int tid = threadIdx.x;
    const int lane = tid & 63;
    const int wid = tid >> 6;          // 8 waves: 2(m) x 4(n)
    const int colk = lane & 31;
    const int half = lane >> 5;
    const int wm = (wid & 1) * 64;
    const int wn = (wid >> 1) * 64;

    const int base_n = blockIdx.x * MT;
    const int ks = blockIdx.y;
    const uint kbase = ks * (KK / KSPLIT);    // 0 or 1024
    const int bq = base_n >> 10;
    const int sb = base_n & (SS - 1);

    // A staging: 512 threads stage 128 latents x 16 d
    const int lat_a = tid & 127;
    const int dqa = (tid >> 7) * 4;
    const float* xb = x + ((size_t)bq * DD + dqa) * SS + sb + lat_a;

    // B staging via glds: wave -> plane p = wid&1, code groups c0, c0+32
    const uint pB = wid & 1;
    const uint c0B = (wid >> 1) * 64;
    const uint codeB = (lane >> 1);                     // within group of 32
    const uint hB = (lane & 1) ^ ((lane >> 3) & 1);     // swizzled half

    floatx16 acc[2][2];
#pragma unroll
    for (int i = 0; i < 2; ++i)
#pragma unroll
        for (int j = 0; j < 2; ++j) acc[i][j] = (floatx16)(0.0f);

    float bestv[2][16];
    int bestc[2][16];
#pragma unroll
    for (int t = 0; t < 2; ++t)
#pragma unroll
        for (int r = 0; r < 16; ++r) { bestv[t][r] = 3.4e38f; bestc[t][r] = 0; }

    // ---- preload chunk 0 (kt=0, dt=0) into buffer 0 ----
    {
        ushort* bp = pB ? &Bl[0][0] : &Bh[0][0];
#pragma unroll
        for (int ii = 0; ii < 2; ++ii) {
            const uint cc = c0B + ii * 32;
            const uint code = kbase + cc + codeB;
            const uint j = pB * 524288u + code * 256u + hB * 8u;  // dt=0
            glds16(e16 + area_us(j), bp + cc * 16);
        }
        float fa[4];
#pragma unroll
        for (int i = 0; i < 4; ++i) fa[i] = xb[(size_t)i * SS];
        ushort h[4], l[4];
#pragma unroll
        for (int i = 0; i < 4; ++i) split16(fa[i], h[i], l[i]);
        uint2 w;
        w.x = (uint)h[0] | ((uint)h[1] << 16);
        w.y = (uint)h[2] | ((uint)h[3] << 16);
        *reinterpret_cast<uint2*>(&Ah[0][lat_a * LDA + dqa]) = w;
        w.x = (uint)l[0] | ((uint)l[1] << 16);
        w.y = (uint)l[2] | ((uint)l[3] << 16);
        *reinterpret_cast<uint2*>(&Al[0][lat_a * LDA + dqa]) = w;
    }
    __syncthreads();   // drains vmcnt (glds) + lgkm (A writes)

    for (int c = 0; c < 64; ++c) {          // 4 kt x 16 dt chunks (K=16 each)
        const int cur = c & 1, nxt = cur ^ 1;
        float fa[4];
        // ---- issue next chunk's B glds + A loads (in flight during MFMA) ----
        if (c < 63) {
            const int c1 = c + 1;
            const uint kt1 = c1 >> 4;
            const uint dt1 = (c1 & 15) * 16;
            ushort* bp = pB ? &Bl[nxt][0] : &Bh[nxt][0];
#pragma unroll
            for (int ii = 0; ii < 2; ++ii) {
                const uint cc = c0B + ii * 32;
                const uint code = kbase + kt1 * NTT + cc + codeB;
                const uint j = pB * 524288u + code * 256u + dt1 + hB * 8u;
                glds16(e16 + area_us(j), bp + cc * 16);
            }
#pragma unroll
            for (int i = 0; i < 4; ++i) fa[i] = xb[(size_t)(dt1 + i) * SS];
        }
        // ---- fragments from current buffer + 12 MFMA (3 terms x 2x2) ----
        const int foA = colk * LDA + half * 8;
        const int hsw = (half ^ ((colk >> 2) & 1)) * 8;   // B swizzle
        half8v ah0 = *reinterpret_cast<const half8v*>(&Ah[cur][foA + wm * LDA]);
        half8v ah1 = *reinterpret_cast<const half8v*>(&Ah[cur][foA + (wm + 32) * LDA]);
        half8v al0 = *reinterpret_cast<const half8v*>(&Al[cur][foA + wm * LDA]);
        half8v al1 = *reinterpret_cast<const half8v*>(&Al[cur][foA + (wm + 32) * LDA]);
        half8v bh0 = *reinterpret_cast<const half8v*>(&Bh[cur][(wn + colk) * 16 + hsw]);
        half8v bh1 = *reinterpret_cast<const half8v*>(&Bh[cur][(wn + 32 + colk) * 16 + hsw]);
        half8v bl0 = *reinterpret_cast<const half8v*>(&Bl[cur][(wn + colk) * 16 + hsw]);
        half8v bl1 = *reinterpret_cast<const half8v*>(&Bl[cur][(wn + 32 + colk) * 16 + hsw]);

        acc[0][0] = MFMA_F16(ah0, bh0, acc[0][0], 0, 0, 0);
        acc[0][0] = MFMA_F16(ah0, bl0, acc[0][0], 0, 0, 0);
        acc[0][0] = MFMA_F16(al0, bh0, acc[0][0], 0, 0, 0);

        acc[0][1] = MFMA_F16(ah0, bh1, acc[0][1], 0, 0, 0);
        acc[0][1] = MFMA_F16(ah0, bl1, acc[0][1], 0, 0, 0);
        acc[0][1] = MFMA_F16(al0, bh1, acc[0][1], 0, 0, 0);

        acc[1][0] = MFMA_F16(ah1, bh0, acc[1][0], 0, 0, 0);
        acc[1][0] = MFMA_F16(ah1, bl0, acc[1][0], 0, 0, 0);
        acc[1][0] = MFMA_F16(al1, bh0, acc[1][0], 0, 0, 0);

        acc[1][1] = MFMA_F16(ah1, bh1, acc[1][1], 0, 0, 0);
        acc[1][1] = MFMA_F16(ah1, bl1, acc[1][1], 0, 0, 0);
        acc[1][1] = MFMA_F16(al1, bh1, acc[1][1], 0, 0, 0);

        // ---- convert prefetched A -> write NEXT buffer (overlaps MFMA) ----
        if (c < 63) {
            ushort h[4], l[4];
#pragma unroll
            for (int i = 0; i < 4; ++i) split16(fa[i], h[i], l[i]);
            uint2 w;
            w.x = (uint)h[0] | ((uint)h[1] << 16);
            w.y = (uint)h[2] | ((uint)h[3] << 16);
            *reinterpret_cast<uint2*>(&Ah[nxt][lat_a * LDA + dqa]) = w;
            w.x = (uint)l[0] | ((uint)l[1] << 16);
            w.y = (uint)l[2] | ((uint)l[3] << 16);
            *reinterpret_cast<uint2*>(&Al[nxt][lat_a * LDA + dqa]) = w;
        }
        // ---- per-kt epilogue: running per-lane argmin, reset acc ----
        if ((c & 15) == 15) {
            const int kt = c >> 4;
            const int cd0 = kbase + kt * NTT + wn + colk;
            const int cd1 = cd0 + 32;
            const float h0 = hn[cd0];
            const float h1 = hn[cd1];
#pragma unroll
            for (int tm = 0; tm < 2; ++tm) {
#pragma unroll
                for (int r = 0; r < 16; ++r) {
                    float s0 = h0 - acc[tm][0][r];
                    float s1 = h1 - acc[tm][1][r];
                    float v = s0; int cd = cd0;
                    if (s1 < s0) { v = s1; cd = cd1; }   // strict <: smaller code wins
                    if (v < bestv[tm][r]) { bestv[tm][r] = v; bestc[tm][r] = cd; }
                    acc[tm][0][r] = 0.f;
                    acc[tm][1][r] = 0.f;
                }
            }
        }
        __syncthreads();   // single barrier/chunk: drains glds + A writes
    }

    // ---- cross-lane argmin over the 32 colk lanes ----
#pragma unroll
    for (int tm = 0; tm < 2; ++tm) {
#pragma unroll
        for (int r = 0; r < 16; ++r) {
            float v = bestv[tm][r];
            int cd = bestc[tm][r];
#pragma unroll
            for (int mk = 1; mk < 32; mk <<= 1) {
                float ov = __shfl_xor(v, mk);
                int oc = __shfl_xor(cd, mk);
                if (ov < v || (ov == v && oc < cd)) { v = ov; cd = oc; }
            }
            if (colk == 0) {
                const int row = (r & 3) + 8 * (r >> 2) + 4 * half;  // verified C/D map
                sv[wid >> 1][wm + tm * 32 + row] = v;
                sc[wid >> 1][wm + tm * 32 + row] = cd;
            }
        }
    }
    __syncthreads();
    // ---- combine 4 n-wave groups, pack u64 key, write to OWN out rows ----
    if (tid < MT) {
        float v = sv[0][tid]; int cd = sc[0][tid];
#pragma unroll
        for (int g = 1; g < 4; ++g) {
            float ov = sv[g][tid]; int oc = sc[g][tid];
            if (ov < v || (ov == v && oc < cd)) { v = ov; cd = oc; }
        }
        ull key = (((ull)mono(v)) << 32) | (uint)cd;
        const int row = 2 * ks + (tid >> 6);     // rows 0..3 (outside Eh/El 4..19)
        ull* p = reinterpret_cast<ull*>(out + ((size_t)(bq * DD + row) * SS + sb));
        p[tid & 63] = key;
    }
}

__global__ __launch_bounds__(256) void gather_kernel(
        const float* __restrict__ emb, float* __restrict__ out) {
    __shared__ int bc[MT];
    const int tid = threadIdx.x;
    const int base_n = blockIdx.x * MT;
    const int bq = base_n >> 10;
    const int sb = base_n & (SS - 1);
    if (tid < MT) {
        const int r = tid >> 6;
        const int cq = tid & 63;
        const ull* p0 = reinterpret_cast<const ull*>(
                out + ((size_t)(bq * DD + r) * SS + sb));
        const ull* p1 = reinterpret_cast<const ull*>(
                out + ((size_t)(bq * DD + 2 + r) * SS + sb));
        ull k0 = p0[cq], k1 = p1[cq];
        ull kb = k0 < k1 ? k0 : k1;
        bc[tid] = (int)(uint)(kb & 0xFFFFFFFFull);
    }
    __syncthreads();
    {
        const int mq = tid & 31;
        const int dg = tid >> 5;
        const int k0 = bc[mq * 4 + 0];
        const int k1 = bc[mq * 4 + 1];
        const int k2 = bc[mq * 4 + 2];
        const int k3 = bc[mq * 4 + 3];
#pragma unroll 4
        for (int dd = 0; dd < 32; ++dd) {
            const int d = dg * 32 + dd;
            const float* er = emb + (size_t)d * KK;
            float4 o = make_float4(er[k0], er[k1], er[k2], er[k3]);
            reinterpret_cast<float4*>(&out[((size_t)bq * DD + d) * SS + sb])[mq] = o;
        }
    }
}

extern "C" void kernel_launch(void* const* d_in, const int* in_sizes, int n_in,
                              void* d_out, int out_size, void* d_ws, size_t ws_size,
                              hipStream_t stream) {
    const float* x = (const float*)d_in[0];     // (32,256,32,32)
    const float* emb = (const float*)d_in[1];   // (256,2048)
    float* out = (float*)d_out;
    float* hn = (float*)d_ws;                   // 8 KB (proven safe)

    hipLaunchKernelGGL(prep_e, dim3(256), dim3(256), 0, stream,
                       emb, (ushort*)d_out);
    hipLaunchKernelGGL(hn_kernel, dim3(KK / 256), dim3(256), 0, stream, emb, hn);
    hipLaunchKernelGGL(vq_fused, dim3(NN / MT, KSPLIT), dim3(512), 0, stream,
                       x, (const ushort*)d_out, hn, out);
    hipLaunchKernelGGL(gather_kernel, dim3(NN / MT), dim3(256), 0, stream,
                       emb, out);
}